// Round 6
// baseline (255.240 us; speedup 1.0000x reference)
//
#include <hip/hip_runtime.h>

#define NB 1024
#define NP 8192
#define HALF_PTS 4096          // points per block (2 blocks per batch)
#define TILE_PTS 1024          // points per LDS tile
#define TILE_F4  768           // float4s per operand tile (1024*3/4)
#define ITERS    4             // HALF_PTS / TILE_PTS

// ---------------- Pass 1: per-half-batch sums: sum(p), sum(q), sum(p q^T) -------------
// Dense coalesced float4 loads -> LDS staging -> point-aligned reads.
// Register prefetch of tile k+1 overlaps compute of tile k.
__global__ __launch_bounds__(256) void cov_kernel(const float* __restrict__ P,
                                                  const float* __restrict__ Q,
                                                  float* __restrict__ sums) {
    const int blk = blockIdx.x;
    const int b = blk >> 1, h = blk & 1;
    const int t = threadIdx.x;
    const float4* P4 = reinterpret_cast<const float4*>(P) + (size_t)b*6144 + h*3072;
    const float4* Q4 = reinterpret_cast<const float4*>(Q) + (size_t)b*6144 + h*3072;

    __shared__ float lp[TILE_PTS*3];   // 12 KB
    __shared__ float lq[TILE_PTS*3];   // 12 KB

    // prefetch tile 0 (dense: lane-contiguous float4s)
    float4 rp0 = P4[t], rp1 = P4[256+t], rp2 = P4[512+t];
    float4 rq0 = Q4[t], rq1 = Q4[256+t], rq2 = Q4[512+t];

    float sp0=0,sp1=0,sp2=0, sq0=0,sq1=0,sq2=0;
    float s00=0,s01=0,s02=0,s10=0,s11=0,s12=0,s20=0,s21=0,s22=0;

    for (int it = 0; it < ITERS; ++it) {
        __syncthreads();   // previous tile's readers done
        float4* wp = reinterpret_cast<float4*>(lp);
        float4* wq = reinterpret_cast<float4*>(lq);
        wp[t] = rp0; wp[256+t] = rp1; wp[512+t] = rp2;
        wq[t] = rq0; wq[256+t] = rq1; wq[512+t] = rq2;
        __syncthreads();
        if (it + 1 < ITERS) {         // issue next tile's loads; drain under compute
            const float4* Pn = P4 + (size_t)(it+1)*TILE_F4;
            const float4* Qn = Q4 + (size_t)(it+1)*TILE_F4;
            rp0 = Pn[t]; rp1 = Pn[256+t]; rp2 = Pn[512+t];
            rq0 = Qn[t]; rq1 = Qn[256+t]; rq2 = Qn[512+t];
        }
        #pragma unroll
        for (int j = 0; j < 4; ++j) {
            const int n3 = 3*(t + 256*j);   // 12B lane stride -> 2-way LDS alias (free)
            const float px = lp[n3], py = lp[n3+1], pz = lp[n3+2];
            const float qx = lq[n3], qy = lq[n3+1], qz = lq[n3+2];
            sp0 += px; sp1 += py; sp2 += pz;
            sq0 += qx; sq1 += qy; sq2 += qz;
            s00 = fmaf(px,qx,s00); s01 = fmaf(px,qy,s01); s02 = fmaf(px,qz,s02);
            s10 = fmaf(py,qx,s10); s11 = fmaf(py,qy,s11); s12 = fmaf(py,qz,s12);
            s20 = fmaf(pz,qx,s20); s21 = fmaf(pz,qy,s21); s22 = fmaf(pz,qz,s22);
        }
    }

    float vals[15] = {sp0,sp1,sp2,sq0,sq1,sq2,s00,s01,s02,s10,s11,s12,s20,s21,s22};
    #pragma unroll
    for (int i = 0; i < 15; ++i) {
        float v = vals[i];
        v += __shfl_down(v, 32, 64);
        v += __shfl_down(v, 16, 64);
        v += __shfl_down(v, 8, 64);
        v += __shfl_down(v, 4, 64);
        v += __shfl_down(v, 2, 64);
        v += __shfl_down(v, 1, 64);
        vals[i] = v;
    }
    __shared__ float red[4][15];
    const int wave = t >> 6, lane = t & 63;
    if (lane == 0) {
        #pragma unroll
        for (int i = 0; i < 15; ++i) red[wave][i] = vals[i];
    }
    __syncthreads();
    if (t < 15) sums[blk*16 + t] = red[0][t] + red[1][t] + red[2][t] + red[3][t];
}

// ---------------- Pass 2: per-batch Kabsch via Horn quaternion method ----------------
// Dominant eigenvector of Horn's 4x4 K matrix == SVD rotation with sign(det)
// correction. Solve by 30x matrix squaring of the PSD shift S=K+2|A|_F I:
// converges to the fp32 conditioning limit regardless of eigen-gap.
__global__ void kabsch_kernel(const float* __restrict__ sums, float* __restrict__ RT) {
    const int b = blockIdx.x * blockDim.x + threadIdx.x;
    if (b >= NB) return;
    const float* sa = sums + (2*b)*16;
    const float* sb = sums + (2*b+1)*16;
    float s[15];
    #pragma unroll
    for (int i = 0; i < 15; ++i) s[i] = sa[i] + sb[i];

    const float invN = 1.0f / (float)NP;
    const float sp[3] = {s[0], s[1], s[2]};
    const float sq[3] = {s[3], s[4], s[5]};
    float M[3][3];
    #pragma unroll
    for (int i = 0; i < 3; ++i)
        #pragma unroll
        for (int j = 0; j < 3; ++j)
            M[i][j] = s[6 + 3*i + j] - sp[i]*sq[j]*invN;

    float fro2 = 0.0f;
    #pragma unroll
    for (int i = 0; i < 3; ++i)
        #pragma unroll
        for (int j = 0; j < 3; ++j)
            fro2 = fmaf(M[i][j], M[i][j], fro2);
    const float shift = 2.0f * sqrtf(fro2) + 1e-30f;

    float S[4][4];
    S[0][0] = M[0][0] + M[1][1] + M[2][2] + shift;
    S[0][1] = M[2][1] - M[1][2];
    S[0][2] = M[0][2] - M[2][0];
    S[0][3] = M[1][0] - M[0][1];
    S[1][1] = M[0][0] - M[1][1] - M[2][2] + shift;
    S[1][2] = M[0][1] + M[1][0];
    S[1][3] = M[0][2] + M[2][0];
    S[2][2] = M[1][1] - M[0][0] - M[2][2] + shift;
    S[2][3] = M[1][2] + M[2][1];
    S[3][3] = M[2][2] - M[0][0] - M[1][1] + shift;
    S[1][0]=S[0][1]; S[2][0]=S[0][2]; S[3][0]=S[0][3];
    S[2][1]=S[1][2]; S[3][1]=S[1][3]; S[3][2]=S[2][3];

    {
        float tr = S[0][0]+S[1][1]+S[2][2]+S[3][3];
        float inv = 1.0f / tr;
        #pragma unroll
        for (int i = 0; i < 4; ++i)
            #pragma unroll
            for (int j = 0; j < 4; ++j) S[i][j] *= inv;
    }
    #pragma unroll 1
    for (int it = 0; it < 30; ++it) {
        float T[4][4];
        #pragma unroll
        for (int i = 0; i < 4; ++i)
            #pragma unroll
            for (int j = 0; j < 4; ++j) {
                float a = 0.0f;
                #pragma unroll
                for (int k = 0; k < 4; ++k) a = fmaf(S[i][k], S[k][j], a);
                T[i][j] = a;
            }
        float tr = T[0][0]+T[1][1]+T[2][2]+T[3][3];
        float inv = 1.0f / tr;
        #pragma unroll
        for (int i = 0; i < 4; ++i)
            #pragma unroll
            for (int j = 0; j < 4; ++j) S[i][j] = T[i][j] * inv;
    }

    int c = 0;
    float best = S[0][0];
    if (S[1][1] > best) { best = S[1][1]; c = 1; }
    if (S[2][2] > best) { best = S[2][2]; c = 2; }
    if (S[3][3] > best) { best = S[3][3]; c = 3; }
    const float qn = rsqrtf(fmaxf(best, 1e-30f));
    const float w = S[0][c]*qn, x = S[1][c]*qn, y = S[2][c]*qn, z = S[3][c]*qn;

    const float R00 = 1.0f-2.0f*(y*y+z*z), R01 = 2.0f*(x*y-w*z), R02 = 2.0f*(x*z+w*y);
    const float R10 = 2.0f*(x*y+w*z), R11 = 1.0f-2.0f*(x*x+z*z), R12 = 2.0f*(y*z-w*x);
    const float R20 = 2.0f*(x*z-w*y), R21 = 2.0f*(y*z+w*x), R22 = 1.0f-2.0f*(x*x+y*y);

    const float pm0=sp[0]*invN, pm1=sp[1]*invN, pm2=sp[2]*invN;
    const float cm0=sq[0]*invN, cm1=sq[1]*invN, cm2=sq[2]*invN;
    const float t0 = pm0 - (R00*cm0 + R01*cm1 + R02*cm2);
    const float t1 = pm1 - (R10*cm0 + R11*cm1 + R12*cm2);
    const float t2 = pm2 - (R20*cm0 + R21*cm1 + R22*cm2);

    float* rt = RT + b*12;
    rt[0]=R00; rt[1]=R01; rt[2]=R02;
    rt[3]=R10; rt[4]=R11; rt[5]=R12;
    rt[6]=R20; rt[7]=R21; rt[8]=R22;
    rt[9]=t0; rt[10]=t1; rt[11]=t2;
}

// ---------------- Pass 3: distances + threshold counts -> partial counts -------------
// Same staging pipeline; each half-batch block writes its integer count (as float)
// to ws. No atomics, no output memset needed.
__global__ __launch_bounds__(256) void gdt_kernel(const float* __restrict__ P,
                                                  const float* __restrict__ Q,
                                                  const float* __restrict__ RT,
                                                  float* __restrict__ partial) {
    const int blk = blockIdx.x;
    const int b = blk >> 1, h = blk & 1;
    const int t = threadIdx.x;
    const float4* P4 = reinterpret_cast<const float4*>(P) + (size_t)b*6144 + h*3072;
    const float4* Q4 = reinterpret_cast<const float4*>(Q) + (size_t)b*6144 + h*3072;
    const float* rt = RT + b*12;
    const float R00=rt[0],R01=rt[1],R02=rt[2],
                R10=rt[3],R11=rt[4],R12=rt[5],
                R20=rt[6],R21=rt[7],R22=rt[8],
                t0=rt[9], t1=rt[10], t2=rt[11];

    __shared__ float lp[TILE_PTS*3];
    __shared__ float lq[TILE_PTS*3];

    float4 rp0 = P4[t], rp1 = P4[256+t], rp2 = P4[512+t];
    float4 rq0 = Q4[t], rq1 = Q4[256+t], rq2 = Q4[512+t];

    int c0=0,c1=0,c2=0,c3=0;
    for (int it = 0; it < ITERS; ++it) {
        __syncthreads();
        float4* wp = reinterpret_cast<float4*>(lp);
        float4* wq = reinterpret_cast<float4*>(lq);
        wp[t] = rp0; wp[256+t] = rp1; wp[512+t] = rp2;
        wq[t] = rq0; wq[256+t] = rq1; wq[512+t] = rq2;
        __syncthreads();
        if (it + 1 < ITERS) {
            const float4* Pn = P4 + (size_t)(it+1)*TILE_F4;
            const float4* Qn = Q4 + (size_t)(it+1)*TILE_F4;
            rp0 = Pn[t]; rp1 = Pn[256+t]; rp2 = Pn[512+t];
            rq0 = Qn[t]; rq1 = Qn[256+t]; rq2 = Qn[512+t];
        }
        #pragma unroll
        for (int j = 0; j < 4; ++j) {
            const int n3 = 3*(t + 256*j);
            const float px = lp[n3], py = lp[n3+1], pz = lp[n3+2];
            const float qx = lq[n3], qy = lq[n3+1], qz = lq[n3+2];
            const float dx = fmaf(R00,qx, fmaf(R01,qy, fmaf(R02,qz, t0))) - px;
            const float dy = fmaf(R10,qx, fmaf(R11,qy, fmaf(R12,qz, t1))) - py;
            const float dz = fmaf(R20,qx, fmaf(R21,qy, fmaf(R22,qz, t2))) - pz;
            const float d2 = fmaf(dx,dx, fmaf(dy,dy, dz*dz));
            c0 += (d2 < 1.0f); c1 += (d2 < 4.0f); c2 += (d2 < 16.0f); c3 += (d2 < 64.0f);
        }
    }

    int c = c0 + c1 + c2 + c3;
    c += __shfl_down(c, 32, 64);
    c += __shfl_down(c, 16, 64);
    c += __shfl_down(c, 8, 64);
    c += __shfl_down(c, 4, 64);
    c += __shfl_down(c, 2, 64);
    c += __shfl_down(c, 1, 64);
    __shared__ int red[4];
    if ((t & 63) == 0) red[t >> 6] = c;
    __syncthreads();
    if (t == 0) partial[blk] = (float)(red[0] + red[1] + red[2] + red[3]);
}

// ---------------- Pass 4: combine half-batch counts -> gdt_ts ----------------
__global__ void finalize_kernel(const float* __restrict__ partial, float* __restrict__ out) {
    const int b = blockIdx.x * blockDim.x + threadIdx.x;
    if (b < NB)
        out[b] = (partial[2*b] + partial[2*b+1]) * (1.0f / (4.0f * (float)NP));
}

extern "C" void kernel_launch(void* const* d_in, const int* in_sizes, int n_in,
                              void* d_out, int out_size, void* d_ws, size_t ws_size,
                              hipStream_t stream) {
    const float* P = (const float*)d_in[0];   // coords_pred [B,N,3]
    const float* Q = (const float*)d_in[1];   // coords      [B,N,3]
    float* out = (float*)d_out;               // gdt_ts [B]

    float* sums    = (float*)d_ws;                                           // 2048*16 f = 128 KB
    float* RT      = (float*)((char*)d_ws + (size_t)2*NB*16*sizeof(float));  // 1024*12 f = 48 KB
    float* partial = (float*)((char*)d_ws + (size_t)(2*NB*16 + NB*12)*sizeof(float)); // 2048 f

    cov_kernel<<<2*NB, 256, 0, stream>>>(P, Q, sums);
    kabsch_kernel<<<NB/256, 256, 0, stream>>>(sums, RT);
    gdt_kernel<<<2*NB, 256, 0, stream>>>(P, Q, RT, partial);
    finalize_kernel<<<NB/256, 256, 0, stream>>>(partial, out);
}